// Round 5
// baseline (815.658 us; speedup 1.0000x reference)
//
#include <hip/hip_runtime.h>
#include <hip/hip_bf16.h>

#define NN 10000
#define NE 320000
#define F_NODE 128
#define F_EDGE 64
#define HID 128
#define LAT 64
#define NPB 4   // nodes per block in layer kernels (1 wave per node)

using bf16 = __hip_bfloat16;
typedef float f32x4 __attribute__((ext_vector_type(4)));

// Runtime-dtype load: isbf selects bf16 vs f32 storage. Wave-uniform flag.
static __device__ __forceinline__ float ldf(const void* p, long i, int isbf) {
    if (isbf) return __bfloat162float(((const bf16*)p)[i]);
    return ((const float*)p)[i];
}

static __device__ __forceinline__ float b2f(unsigned short u) {
    return __uint_as_float(((unsigned int)u) << 16);
}

// load 2 consecutive elements (pair index = lane) from row `row` of a matrix
// with C2 pairs per row. BF=1: bf16 storage (4B load), BF=0: f32 (8B load).
template<int BF>
static __device__ __forceinline__ float2 ld2v(const void* p, int row, int C2, int lane) {
    long idx = (long)row * C2 + lane;
    if (BF) {
        ushort2 v = ((const ushort2*)p)[idx];
        return make_float2(b2f(v.x), b2f(v.y));
    }
    return ((const float2*)p)[idx];
}

// ---------------- dtype detectors ----------------
// flags[0]=nf, flags[1]=ef, flags[2..13]=Wn1,bn1,We1,be1,Wm1,bm1,Wn2,bn2,We2,be2,Wm2,bm2
//   (1 = bf16 storage, 0 = f32 storage)
// flags[14]=src int64?, flags[15]=dst int64?  (1 = int64 words)
__global__ void k_detect(const void* nf, const void* ef,
                         const void* w0, const void* w1, const void* w2, const void* w3,
                         const void* w4, const void* w5, const void* w6, const void* w7,
                         const void* w8, const void* w9, const void* w10, const void* w11,
                         const int* srcp, const int* dstp, int* __restrict__ flags) {
    const void* ps[14] = {nf, ef, w0, w1, w2, w3, w4, w5, w6, w7, w8, w9, w10, w11};
    const int lens[14] = {NN * F_NODE, NE * F_EDGE,
                          16384, 128, 8192, 128, 16384, 128,
                          8192, 64, 4096, 64, 4096, 64};
    __shared__ int cntr;
    if (threadIdx.x == 0) cntr = 0;
    __syncthreads();
    int b = blockIdx.x;
    if (b < 14) {
        // f32 storage: even ushorts are low mantissa halves -> exponent field
        // ~uniform random (~72% outside [90,160]). bf16 storage: sane exponents.
        const unsigned short* raw = (const unsigned short*)ps[b];
        int S = lens[b] / 2; if (S > 2048) S = 2048;
        int c = 0;
        for (int i = threadIdx.x; i < S; i += 256) {
            unsigned short u = raw[2 * i];
            int e = (u >> 7) & 0xFF;
            if (e < 90 || e > 160) c++;
        }
        atomicAdd(&cntr, c);
        __syncthreads();
        if (threadIdx.x == 0) flags[b] = (10 * cntr > 3 * S) ? 0 : 1;
    } else {
        // int64 storage: odd words are high halves of small nonneg ints -> 0.
        const int* raw = (b == 14) ? srcp : dstp;
        int S = 2048;
        int c = 0;
        for (int i = threadIdx.x; i < S; i += 256) {
            if (raw[2 * i + 1] == 0) c++;
        }
        atomicAdd(&cntr, c);
        __syncthreads();
        if (threadIdx.x == 0) flags[b] = (2 * cntr > S) ? 1 : 0;
    }
}

// ---------------- weight/bias normalization to f32 ----------------
__global__ void k_convert_w(const void* w0, const void* w1, const void* w2, const void* w3,
                            const void* w4, const void* w5, const void* w6, const void* w7,
                            const void* w8, const void* w9, const void* w10, const void* w11,
                            const int* __restrict__ flags, float* __restrict__ wf) {
    const int WLEN[12] = {16384, 128, 8192, 128, 16384, 128, 8192, 64, 4096, 64, 4096, 64};
    const int WOFF[12] = {0, 16384, 16512, 24704, 24832, 41216, 41344, 49536, 49600, 53696, 53760, 57856};
    const void* ps[12] = {w0, w1, w2, w3, w4, w5, w6, w7, w8, w9, w10, w11};
    int t = blockIdx.x >> 6;
    int i = (blockIdx.x & 63) * 256 + threadIdx.x;
    if (i < WLEN[t]) wf[WOFF[t] + i] = ldf(ps[t], i, flags[2 + t]);
}

// ---------------- CSR build ----------------

__global__ void k_count(const int* __restrict__ dstp, const int* __restrict__ flags,
                        int* __restrict__ cnt) {
    int e = blockIdx.x * 256 + threadIdx.x;
    int w = flags[15];
    if (e < NE) atomicAdd(&cnt[dstp[(long)e << w]], 1);
}

// 1024 threads; thread t serially scans 10 consecutive elements, wave-level
// __shfl_up scan of per-thread sums, then 16 wave sums scanned by thread 0.
__global__ void k_scan(const int* __restrict__ cnt, int* __restrict__ row_start) {
    __shared__ int wsum[16];
    int t = threadIdx.x;
    int base = t * 10;
    int v[10];
    int s = 0;
#pragma unroll
    for (int i = 0; i < 10; i++) {
        v[i] = (base + i < NN) ? cnt[base + i] : 0;
        s += v[i];
    }
    int lane = t & 63;
    int x = s;
#pragma unroll
    for (int off = 1; off < 64; off <<= 1) {
        int y = __shfl_up(x, off, 64);
        if (lane >= off) x += y;
    }
    if (lane == 63) wsum[t >> 6] = x;
    __syncthreads();
    if (t == 0) {
        int c = 0;
#pragma unroll
        for (int i = 0; i < 16; i++) { int tmp = wsum[i]; wsum[i] = c; c += tmp; }
        row_start[NN] = c;
    }
    __syncthreads();
    int excl = wsum[t >> 6] + x - s;   // exclusive prefix at this thread's chunk start
#pragma unroll
    for (int i = 0; i < 10; i++) {
        if (base + i < NN) row_start[base + i] = excl;
        excl += v[i];
    }
}

__global__ void k_fill(const int* __restrict__ srcp, const int* __restrict__ dstp,
                       const int* __restrict__ flags,
                       const int* __restrict__ row_start, int* __restrict__ fill,
                       int2* __restrict__ epack) {
    int e = blockIdx.x * 256 + threadIdx.x;
    int ws_ = flags[14], wd = flags[15];
    if (e < NE) {
        int d = dstp[(long)e << wd];
        int s = srcp[(long)e << ws_];
        int pos = row_start[d] + atomicAdd(&fill[d], 1);
        epack[pos] = make_int2(e, s);
    }
}

// ---------------- Layer 1 gather chunk (addresses pre-staged in LDS) ----------
template<int FN, int FE>
static __device__ __forceinline__ void l1_chunk(
        const void* nf, const void* ef, const int2* e, int m, int lane,
        float& ax0, float& ax1, float& ae0, float& ae1) {
    int i = 0;
    for (; i + 4 <= m; i += 4) {
        int2 p0 = e[i], p1 = e[i + 1], p2 = e[i + 2], p3 = e[i + 3];
        float2 x0 = ld2v<FN>(nf, p0.y, 64, lane);
        float2 x1 = ld2v<FN>(nf, p1.y, 64, lane);
        float2 x2 = ld2v<FN>(nf, p2.y, 64, lane);
        float2 x3 = ld2v<FN>(nf, p3.y, 64, lane);
        ax0 += (x0.x + x1.x) + (x2.x + x3.x);
        ax1 += (x0.y + x1.y) + (x2.y + x3.y);
        if (lane < 32) {
            float2 e0 = ld2v<FE>(ef, p0.x, 32, lane);
            float2 e1 = ld2v<FE>(ef, p1.x, 32, lane);
            float2 e2 = ld2v<FE>(ef, p2.x, 32, lane);
            float2 e3 = ld2v<FE>(ef, p3.x, 32, lane);
            ae0 += (e0.x + e1.x) + (e2.x + e3.x);
            ae1 += (e0.y + e1.y) + (e2.y + e3.y);
        }
    }
    for (; i < m; ++i) {
        int2 p = e[i];
        float2 x = ld2v<FN>(nf, p.y, 64, lane);
        ax0 += x.x; ax1 += x.y;
        if (lane < 32) {
            float2 ev = ld2v<FE>(ef, p.x, 32, lane);
            ae0 += ev.x; ae1 += ev.y;
        }
    }
}

// ---------------- Layer 1 ----------------
// 256 threads = 4 waves = 4 nodes. Gather: wave w owns node n0+w; per chunk of
// <=128 edges the wave stages epack into LDS (coalesced) then runs a 4x-unrolled
// gather with all addresses available -> deep VMEM pipelining. Lane covers 2
// columns via one 4B(bf16)/8B(f32) load. Matmul: thread (c=t&127, h=t>>7)
// computes nodes {2h, 2h+1} sharing each weight load.
__global__ __launch_bounds__(256) void k_layer1(
        const void* __restrict__ nf, const void* __restrict__ ef,
        const int* __restrict__ flags,
        const int* __restrict__ row_start, const int* __restrict__ cnt,
        const int2* __restrict__ epack,
        const float* __restrict__ Wn1, const float* __restrict__ bn1,
        const float* __restrict__ We1, const float* __restrict__ be1,
        const float* __restrict__ Wm1, const float* __restrict__ bm1,
        float* __restrict__ h1, float* __restrict__ bvec) {
    int n0 = blockIdx.x * NPB;
    int t = threadIdx.x;
    int w = t >> 6, lane = t & 63;
    __shared__ int2 eph[NPB][128];
    __shared__ __align__(16) float a_s[NPB][F_NODE];
    __shared__ __align__(16) float b_s[NPB][F_EDGE];
    __shared__ __align__(16) float t_s[NPB][HID];
    __shared__ int deg_s[NPB];

    int fn = flags[0], fe = flags[1];
    int n = n0 + w;
    int start = row_start[n], deg = cnt[n];
    if (lane == 0) deg_s[w] = deg;

    float ax0 = 0.f, ax1 = 0.f, ae0 = 0.f, ae1 = 0.f;
    for (int base = 0; base < deg; base += 128) {
        int m = min(128, deg - base);
        if (lane < m)      eph[w][lane]      = epack[start + base + lane];
        if (64 + lane < m) eph[w][64 + lane] = epack[start + base + 64 + lane];
        // wave-local LDS produce->consume: compiler orders via lgkmcnt
        if (fn) { if (fe) l1_chunk<1,1>(nf, ef, eph[w], m, lane, ax0, ax1, ae0, ae1);
                  else    l1_chunk<1,0>(nf, ef, eph[w], m, lane, ax0, ax1, ae0, ae1); }
        else    { if (fe) l1_chunk<0,1>(nf, ef, eph[w], m, lane, ax0, ax1, ae0, ae1);
                  else    l1_chunk<0,0>(nf, ef, eph[w], m, lane, ax0, ax1, ae0, ae1); }
    }
    float inv = (deg > 0) ? (1.f / (float)deg) : 0.f;
    *(float2*)&a_s[w][2 * lane] = make_float2(ax0 * inv, ax1 * inv);
    if (lane < 32) {
        float2 b = make_float2(ae0 * inv, ae1 * inv);
        *(float2*)&b_s[w][2 * lane] = b;
        *(float2*)&bvec[(long)n * F_EDGE + 2 * lane] = b;
    }
    __syncthreads();

    // stage 1: t_s = a@Wn1 + b@We1 + bn1 + be1
    const int c = t & 127, hh = t >> 7;
    const int la = 2 * hh, lb = 2 * hh + 1;
    float o0 = bn1[c] + be1[c];
    float o1 = o0;
    for (int k = 0; k < F_NODE; k += 4) {
        float w0 = Wn1[(k + 0) * HID + c];
        float w1 = Wn1[(k + 1) * HID + c];
        float w2 = Wn1[(k + 2) * HID + c];
        float w3 = Wn1[(k + 3) * HID + c];
        float4 aA = *(const float4*)&a_s[la][k];
        float4 aB = *(const float4*)&a_s[lb][k];
        o0 += aA.x * w0 + aA.y * w1 + aA.z * w2 + aA.w * w3;
        o1 += aB.x * w0 + aB.y * w1 + aB.z * w2 + aB.w * w3;
    }
    for (int k = 0; k < F_EDGE; k += 4) {
        float w0 = We1[(k + 0) * HID + c];
        float w1 = We1[(k + 1) * HID + c];
        float w2 = We1[(k + 2) * HID + c];
        float w3 = We1[(k + 3) * HID + c];
        float4 aA = *(const float4*)&b_s[la][k];
        float4 aB = *(const float4*)&b_s[lb][k];
        o0 += aA.x * w0 + aA.y * w1 + aA.z * w2 + aA.w * w3;
        o1 += aB.x * w0 + aB.y * w1 + aB.z * w2 + aB.w * w3;
    }
    t_s[la][c] = o0;
    t_s[lb][c] = o1;
    __syncthreads();

    // stage 2: h1 = relu(t_s @ Wm1 + bm1)
    float p0 = bm1[c], p1 = p0;
    for (int k = 0; k < HID; k += 4) {
        float w0 = Wm1[(k + 0) * HID + c];
        float w1 = Wm1[(k + 1) * HID + c];
        float w2 = Wm1[(k + 2) * HID + c];
        float w3 = Wm1[(k + 3) * HID + c];
        float4 aA = *(const float4*)&t_s[la][k];
        float4 aB = *(const float4*)&t_s[lb][k];
        p0 += aA.x * w0 + aA.y * w1 + aA.z * w2 + aA.w * w3;
        p1 += aB.x * w0 + aB.y * w1 + aB.z * w2 + aB.w * w3;
    }
    if (deg_s[la] == 0) p0 = 0.f;
    if (deg_s[lb] == 0) p1 = 0.f;
    h1[(long)(n0 + la) * HID + c] = fmaxf(p0, 0.f);
    h1[(long)(n0 + lb) * HID + c] = fmaxf(p1, 0.f);
}

// ---------------- Layer 2 ----------------
// Same wave-per-node gather on h1 (f32). Matmul: wave l handles node n0+l,
// lane = output col (64 cols).
__global__ __launch_bounds__(256) void k_layer2(
        const float* __restrict__ h1, const float* __restrict__ bvec,
        const int* __restrict__ row_start, const int* __restrict__ cnt,
        const int2* __restrict__ epack,
        const float* __restrict__ Wn2, const float* __restrict__ bn2,
        const float* __restrict__ We2, const float* __restrict__ be2,
        const float* __restrict__ Wm2, const float* __restrict__ bm2,
        float* __restrict__ z, float* __restrict__ zout) {
    int n0 = blockIdx.x * NPB;
    int t = threadIdx.x;
    int w = t >> 6, lane = t & 63;
    __shared__ int2 eph[NPB][128];
    __shared__ __align__(16) float a_s[NPB][HID];
    __shared__ __align__(16) float b_s[NPB][F_EDGE];
    __shared__ __align__(16) float t_s[NPB][LAT];

    int n = n0 + w;
    int start = row_start[n], deg = cnt[n];

    const float2* h12 = (const float2*)h1;
    float ax0 = 0.f, ax1 = 0.f;
    for (int base = 0; base < deg; base += 128) {
        int m = min(128, deg - base);
        if (lane < m)      eph[w][lane]      = epack[start + base + lane];
        if (64 + lane < m) eph[w][64 + lane] = epack[start + base + 64 + lane];
        int i = 0;
        for (; i + 4 <= m; i += 4) {
            int2 p0 = eph[w][i], p1 = eph[w][i + 1], p2 = eph[w][i + 2], p3 = eph[w][i + 3];
            float2 x0 = h12[(long)p0.y * 64 + lane];
            float2 x1 = h12[(long)p1.y * 64 + lane];
            float2 x2 = h12[(long)p2.y * 64 + lane];
            float2 x3 = h12[(long)p3.y * 64 + lane];
            ax0 += (x0.x + x1.x) + (x2.x + x3.x);
            ax1 += (x0.y + x1.y) + (x2.y + x3.y);
        }
        for (; i < m; ++i) {
            int2 p = eph[w][i];
            float2 x = h12[(long)p.y * 64 + lane];
            ax0 += x.x; ax1 += x.y;
        }
    }
    float inv = (deg > 0) ? (1.f / (float)deg) : 0.f;
    *(float2*)&a_s[w][2 * lane] = make_float2(ax0 * inv, ax1 * inv);
    if (lane < 32)
        *(float2*)&b_s[w][2 * lane] = ((const float2*)bvec)[(long)n * 32 + lane];
    __syncthreads();

    // stage 1: wave w computes node n's 64 outputs (lane = col)
    const int c = lane;
    float o = bn2[c] + be2[c];
    for (int k = 0; k < HID; k += 4) {
        float w0 = Wn2[(k + 0) * LAT + c];
        float w1 = Wn2[(k + 1) * LAT + c];
        float w2 = Wn2[(k + 2) * LAT + c];
        float w3 = Wn2[(k + 3) * LAT + c];
        float4 a = *(const float4*)&a_s[w][k];
        o += a.x * w0 + a.y * w1 + a.z * w2 + a.w * w3;
    }
    for (int k = 0; k < F_EDGE; k += 4) {
        float w0 = We2[(k + 0) * LAT + c];
        float w1 = We2[(k + 1) * LAT + c];
        float w2 = We2[(k + 2) * LAT + c];
        float w3 = We2[(k + 3) * LAT + c];
        float4 a = *(const float4*)&b_s[w][k];
        o += a.x * w0 + a.y * w1 + a.z * w2 + a.w * w3;
    }
    t_s[w][c] = o;
    __syncthreads();

    float pz = bm2[c];
    for (int k = 0; k < LAT; k += 4) {
        float w0 = Wm2[(k + 0) * LAT + c];
        float w1 = Wm2[(k + 1) * LAT + c];
        float w2 = Wm2[(k + 2) * LAT + c];
        float w3 = Wm2[(k + 3) * LAT + c];
        float4 a = *(const float4*)&t_s[w][k];
        pz += a.x * w0 + a.y * w1 + a.z * w2 + a.w * w3;
    }
    if (deg == 0) pz = 0.f;
    z[(long)n * LAT + c] = pz;
    zout[(long)n * LAT + c] = pz;
}

// ---------------- adj = sigmoid(z @ z^T), f32 out ----------------
// Full grid (r2 version — measured faster than symmetric+mirror). 128x128 tile
// per 256-thread block, 8x8 per thread, K=64 fully in LDS, XOR-swizzled float4
// rows, nontemporal coalesced stores.
__global__ __launch_bounds__(256, 2) void k_adj(const float* __restrict__ z,
                                                float* __restrict__ out) {
    __shared__ float As[128 * 64];
    __shared__ float Bs[128 * 64];
    const int t  = threadIdx.x;
    const int tx = t & 15;
    const int ty = t >> 4;
    const int r0 = blockIdx.y * 128;
    const int c0 = blockIdx.x * 128;

    float4* As4w = (float4*)As;
    float4* Bs4w = (float4*)Bs;
#pragma unroll
    for (int it = 0; it < 8; ++it) {
        int idx = it * 256 + t;           // 0..2047
        int row = idx >> 4;               // 0..127
        int kq  = idx & 15;               // float4 index along k
        int sw  = (row >> 3) & 7;         // XOR swizzle (in float4 units)
        int gra = r0 + row;
        int grb = c0 + row;
        float4 va = make_float4(0.f, 0.f, 0.f, 0.f);
        float4 vb = make_float4(0.f, 0.f, 0.f, 0.f);
        if (gra < NN) va = *(const float4*)(z + (size_t)gra * LAT + kq * 4);
        if (grb < NN) vb = *(const float4*)(z + (size_t)grb * LAT + kq * 4);
        As4w[row * 16 + (kq ^ sw)] = va;
        Bs4w[row * 16 + (kq ^ sw)] = vb;
    }
    __syncthreads();

    float acc[8][8] = {};
    const float4* As4 = (const float4*)As;
    const float4* Bs4 = (const float4*)Bs;
    const int sa = ty & 7;
    const int sb = tx & 7;

    for (int kb = 0; kb < 16; ++kb) {
        float4 a4[8], b4[8];
#pragma unroll
        for (int i = 0; i < 8; ++i)
            a4[i] = As4[(ty * 8 + i) * 16 + (kb ^ sa)];
#pragma unroll
        for (int j = 0; j < 8; ++j)
            b4[j] = Bs4[(tx * 8 + j) * 16 + (kb ^ sb)];
#pragma unroll
        for (int i = 0; i < 8; ++i)
#pragma unroll
            for (int j = 0; j < 8; ++j) {
                acc[i][j] += a4[i].x * b4[j].x;
                acc[i][j] += a4[i].y * b4[j].y;
                acc[i][j] += a4[i].z * b4[j].z;
                acc[i][j] += a4[i].w * b4[j].w;
            }
    }

#pragma unroll
    for (int i = 0; i < 8; ++i) {
        int gr = r0 + ty * 8 + i;
        if (gr >= NN) continue;
#pragma unroll
        for (int jj = 0; jj < 2; ++jj) {
            int gc = c0 + tx * 8 + jj * 4;
            if (gc + 3 < NN) {               // NN % 4 == 0: all-or-nothing per float4
                f32x4 pk;
                pk.x = 1.f / (1.f + __expf(-acc[i][jj * 4 + 0]));
                pk.y = 1.f / (1.f + __expf(-acc[i][jj * 4 + 1]));
                pk.z = 1.f / (1.f + __expf(-acc[i][jj * 4 + 2]));
                pk.w = 1.f / (1.f + __expf(-acc[i][jj * 4 + 3]));
                __builtin_nontemporal_store(pk, (f32x4*)(out + (size_t)gr * NN + gc));
            }
        }
    }
}

// ---------------- launch ----------------

extern "C" void kernel_launch(void* const* d_in, const int* in_sizes, int n_in,
                              void* d_out, int out_size, void* d_ws, size_t ws_size,
                              hipStream_t stream) {
    const void* nf  = d_in[0];
    const void* ef  = d_in[1];
    const int*  src = (const int*)d_in[2];
    const int*  dst = (const int*)d_in[3];
    const void* W[12];
    for (int i = 0; i < 12; i++) W[i] = d_in[4 + i];

    char* ws = (char*)d_ws;
    size_t off = 0;
    auto alloc = [&](size_t bytes) -> void* {
        void* p = ws + off;
        off = (off + bytes + 255) & ~(size_t)255;
        return p;
    };
    int*   flags     = (int*)alloc(16 * sizeof(int));
    float* wf        = (float*)alloc(57920 * sizeof(float));
    int*   cnt       = (int*)alloc(NN * sizeof(int));
    int*   fill      = (int*)alloc(NN * sizeof(int));
    int*   row_start = (int*)alloc((NN + 1) * sizeof(int));
    int2*  epack     = (int2*)alloc((size_t)NE * sizeof(int2));
    float* bvec      = (float*)alloc((size_t)NN * F_EDGE * sizeof(float));
    float* h1        = (float*)alloc((size_t)NN * HID * sizeof(float));
    float* zf        = (float*)alloc((size_t)NN * LAT * sizeof(float));

    hipMemsetAsync(cnt, 0, NN * sizeof(int), stream);
    hipMemsetAsync(fill, 0, NN * sizeof(int), stream);

    k_detect<<<16, 256, 0, stream>>>(nf, ef,
        W[0], W[1], W[2], W[3], W[4], W[5], W[6], W[7], W[8], W[9], W[10], W[11],
        src, dst, flags);
    k_convert_w<<<12 * 64, 256, 0, stream>>>(
        W[0], W[1], W[2], W[3], W[4], W[5], W[6], W[7], W[8], W[9], W[10], W[11],
        flags, wf);

    k_count<<<(NE + 255) / 256, 256, 0, stream>>>(dst, flags, cnt);
    k_scan<<<1, 1024, 0, stream>>>(cnt, row_start);
    k_fill<<<(NE + 255) / 256, 256, 0, stream>>>(src, dst, flags, row_start, fill, epack);

    const float* Wn1 = wf + 0,     *bn1 = wf + 16384;
    const float* We1 = wf + 16512, *be1 = wf + 24704;
    const float* Wm1 = wf + 24832, *bm1 = wf + 41216;
    const float* Wn2 = wf + 41344, *bn2 = wf + 49536;
    const float* We2 = wf + 49600, *be2 = wf + 53696;
    const float* Wm2 = wf + 53760, *bm2 = wf + 57856;

    k_layer1<<<NN / NPB, 256, 0, stream>>>(nf, ef, flags, row_start, cnt, epack,
                                           Wn1, bn1, We1, be1, Wm1, bm1, h1, bvec);
    k_layer2<<<NN / NPB, 256, 0, stream>>>(h1, bvec, row_start, cnt, epack,
                                           Wn2, bn2, We2, be2, Wm2, bm2,
                                           zf, (float*)d_out);

    dim3 g((NN + 127) / 128, (NN + 127) / 128);
    k_adj<<<g, 256, 0, stream>>>(zf, (float*)d_out + (size_t)NN * LAT);
}